// Round 1
// baseline (271.017 us; speedup 1.0000x reference)
//
#include <hip/hip_runtime.h>

// LDS forward collapsed to causal conv:
//   y[b,t,o] = sum_{d<=t} x[b,t-d] * K[d,o] + G[t,o]
//   K[d,o] = sum_s C[s,o] A[s]^d B[s]  (+ M[o,0,d-1] for d in 1..5)
//   G[t,o] = sum_s C[s,o] A[s]^{t+1} h0[s]

#define SEQ_T 512
#define NSTATE 512
#define NOUT 512
#define NBATCH 256

typedef __attribute__((ext_vector_type(8))) short short8v;
typedef __attribute__((ext_vector_type(4))) float float4v;

static __device__ __forceinline__ unsigned short f2bf(float f) {
    union { float f; unsigned int u; } x; x.f = f;
    unsigned int r = x.u + 0x7fffu + ((x.u >> 16) & 1u);  // RNE
    return (unsigned short)(r >> 16);
}

// K1: PBT[s][d] = A[s]^d * B[s];  PHT[s][d] = A[s]^(d+1) * h0[s]
__global__ __launch_bounds__(512) void k_tables(const float* __restrict__ A,
                                                const float* __restrict__ B,
                                                const float* __restrict__ h0,
                                                float* __restrict__ PBT,
                                                float* __restrict__ PHT) {
    int s = blockIdx.x;
    int d = threadIdx.x;
    float a = A[s];
    float r = 1.0f, base = a;
    #pragma unroll
    for (int bit = 0; bit < 9; ++bit) {           // d < 512
        if (d & (1 << bit)) r *= base;
        base *= base;
    }
    PBT[s * 512 + d] = r * B[s];
    PHT[s * 512 + d] = r * a * h0[s];
}

// K2: KT[o][d] (bf16, o-major) and G[t][o] (f32)
__global__ __launch_bounds__(256) void k_ktg(const float* __restrict__ C,
                                             const float* __restrict__ M,
                                             const float* __restrict__ PBT,
                                             const float* __restrict__ PHT,
                                             unsigned short* __restrict__ KT,
                                             float* __restrict__ G) {
    const int o  = blockIdx.y * 256 + threadIdx.x;
    const int d0 = blockIdx.x * 4;
    float kt[4] = {0.f, 0.f, 0.f, 0.f};
    float gg[4] = {0.f, 0.f, 0.f, 0.f};
    for (int s = 0; s < 512; ++s) {
        float c = C[s * 512 + o];
        const float* pb = PBT + s * 512 + d0;   // wave-uniform -> scalar loads
        const float* ph = PHT + s * 512 + d0;
        #pragma unroll
        for (int j = 0; j < 4; ++j) {
            kt[j] = fmaf(pb[j], c, kt[j]);
            gg[j] = fmaf(ph[j], c, gg[j]);
        }
    }
    #pragma unroll
    for (int j = 0; j < 4; ++j) {
        int d = d0 + j;
        float v = kt[j];
        if (d >= 1 && d <= 5) v += M[o * 5 + (d - 1)];   // AR taps
        KT[o * 512 + d] = f2bf(v);
        G[d * 512 + o]  = gg[j];
    }
}

// K3: per batch, Y[b] = Toep(x[b]) @ K + G.  Tile 128x128, 4 waves of 64x64.
__global__ __launch_bounds__(256) void k_main(const float* __restrict__ x,
                                              const unsigned short* __restrict__ KT,
                                              const float* __restrict__ G,
                                              float* __restrict__ out) {
    __shared__ short8v xoct[1024];   // xoct[j] = {xe[j], ..., xe[j+7]}, 16 KB
    __shared__ float xls[512];

    const int b   = blockIdx.z;
    const int bt0 = blockIdx.y * 128;
    const int bo0 = blockIdx.x * 128;
    const int tid = threadIdx.x;

    // stage x[b] (f32) into LDS
    xls[tid]       = x[b * 512 + tid];
    xls[tid + 256] = x[b * 512 + tid + 256];
    __syncthreads();

    // build xe-octet table: xe[i] = (i<=511) ? x[511-i] : 0
    #pragma unroll
    for (int q = 0; q < 4; ++q) {
        int e = tid * 4 + q;
        short8v v;
        #pragma unroll
        for (int jj = 0; jj < 8; ++jj) {
            int i = e + jj;
            float f = (i < 512) ? xls[511 - i] : 0.0f;
            v[jj] = (short)f2bf(f);
        }
        xoct[e] = v;
    }
    __syncthreads();

    const int lane = tid & 63;
    const int w    = tid >> 6;
    const int wm   = w >> 1, wn = w & 1;
    const int t0w  = bt0 + wm * 64;
    const int o0w  = bo0 + wn * 64;
    const int lrow = lane & 15;
    const int g    = lane >> 4;

    float4v acc[4][4];
    #pragma unroll
    for (int mi = 0; mi < 4; ++mi)
        #pragma unroll
        for (int ni = 0; ni < 4; ++ni)
            acc[mi][ni] = (float4v)(0.0f);

    // A-fragment entry index (in xoct entries) at ks=0, per m-block
    int aent[4];
    const unsigned short* bptr[4];
    #pragma unroll
    for (int i = 0; i < 4; ++i) {
        aent[i] = 511 - (t0w + i * 16 + lrow) + g * 8;            // in [0,535]
        bptr[i] = KT + (o0w + i * 16 + lrow) * 512 + g * 8;       // k-contiguous
    }

    for (int ks = 0; ks < 16; ++ks) {
        short8v a[4], bf[4];
        #pragma unroll
        for (int i = 0; i < 4; ++i)
            a[i] = xoct[aent[i] + ks * 32];
        #pragma unroll
        for (int i = 0; i < 4; ++i)
            bf[i] = *(const short8v*)(bptr[i] + ks * 32);
        #pragma unroll
        for (int mi = 0; mi < 4; ++mi)
            #pragma unroll
            for (int ni = 0; ni < 4; ++ni)
                acc[mi][ni] = __builtin_amdgcn_mfma_f32_16x16x32_bf16(
                    a[mi], bf[ni], acc[mi][ni], 0, 0, 0);
    }

    // epilogue: add G, store.  D layout: col = lane&15, row = (lane>>4)*4 + r
    float* outb = out + (size_t)b * 512 * 512;
    #pragma unroll
    for (int mi = 0; mi < 4; ++mi) {
        #pragma unroll
        for (int ni = 0; ni < 4; ++ni) {
            const int o = o0w + ni * 16 + lrow;
            #pragma unroll
            for (int r = 0; r < 4; ++r) {
                const int t = t0w + mi * 16 + g * 4 + r;
                outb[t * 512 + o] = acc[mi][ni][r] + G[t * 512 + o];
            }
        }
    }
}

extern "C" void kernel_launch(void* const* d_in, const int* in_sizes, int n_in,
                              void* d_out, int out_size, void* d_ws, size_t ws_size,
                              hipStream_t stream) {
    const float* x  = (const float*)d_in[0];   // [256,512,1]
    const float* A  = (const float*)d_in[1];   // [512]
    const float* B  = (const float*)d_in[2];   // [1,512]
    const float* C  = (const float*)d_in[3];   // [512,512]
    const float* M  = (const float*)d_in[4];   // [512,1,5]
    const float* h0 = (const float*)d_in[5];   // [512]
    float* out = (float*)d_out;

    char* ws = (char*)d_ws;
    float*          PBT = (float*)ws;                              // 1 MB
    float*          PHT = (float*)(ws + (1u << 20));               // 1 MB
    unsigned short* KT  = (unsigned short*)(ws + (2u << 20));      // 512 KB
    float*          G   = (float*)(ws + (2u << 20) + (1u << 19));  // 1 MB

    k_tables<<<512, 512, 0, stream>>>(A, B, h0, PBT, PHT);
    k_ktg<<<dim3(128, 2), 256, 0, stream>>>(C, M, PBT, PHT, KT, G);
    k_main<<<dim3(4, 4, 256), 256, 0, stream>>>(x, KT, G, out);
}

// Round 2
// 264.841 us; speedup vs baseline: 1.0233x; 1.0233x over previous
//
#include <hip/hip_runtime.h>

// LDS forward collapsed to causal conv:
//   y[b,t,o] = sum_{d<=t} x[b,t-d] * K[d,o] + G[t,o]
//   K[d,o] = sum_s C[s,o] A[s]^d B[s]  (+ M[o,0,d-1] for d in 1..5)
//   G[t,o] = sum_s C[s,o] A[s]^{t+1} h0[s]

typedef __attribute__((ext_vector_type(8))) short short8v;
typedef __attribute__((ext_vector_type(4))) float float4v;

static __device__ __forceinline__ unsigned short f2bf(float f) {
    union { float f; unsigned int u; } x; x.f = f;
    unsigned int r = x.u + 0x7fffu + ((x.u >> 16) & 1u);  // RNE
    return (unsigned short)(r >> 16);
}

// K1: PBT[s][d] = A[s]^d * B[s];  PHT[s][d] = A[s]^(d+1) * h0[s]
__global__ __launch_bounds__(512) void k_tables(const float* __restrict__ A,
                                                const float* __restrict__ B,
                                                const float* __restrict__ h0,
                                                float* __restrict__ PBT,
                                                float* __restrict__ PHT) {
    int s = blockIdx.x;
    int d = threadIdx.x;
    float a = A[s];
    float r = 1.0f, base = a;
    #pragma unroll
    for (int bit = 0; bit < 9; ++bit) {           // d < 512
        if (d & (1 << bit)) r *= base;
        base *= base;
    }
    PBT[s * 512 + d] = r * B[s];
    PHT[s * 512 + d] = r * a * h0[s];
}

// K2: KT[o][d] (bf16, o-major) and G[t][o] (f32)
__global__ __launch_bounds__(256) void k_ktg(const float* __restrict__ C,
                                             const float* __restrict__ M,
                                             const float* __restrict__ PBT,
                                             const float* __restrict__ PHT,
                                             unsigned short* __restrict__ KT,
                                             float* __restrict__ G) {
    const int o  = blockIdx.y * 256 + threadIdx.x;
    const int d0 = blockIdx.x * 4;
    float kt[4] = {0.f, 0.f, 0.f, 0.f};
    float gg[4] = {0.f, 0.f, 0.f, 0.f};
    #pragma unroll 8
    for (int s = 0; s < 512; ++s) {
        float c = C[s * 512 + o];
        const float* pb = PBT + s * 512 + d0;   // wave-uniform -> scalar loads
        const float* ph = PHT + s * 512 + d0;
        #pragma unroll
        for (int j = 0; j < 4; ++j) {
            kt[j] = fmaf(pb[j], c, kt[j]);
            gg[j] = fmaf(ph[j], c, gg[j]);
        }
    }
    #pragma unroll
    for (int j = 0; j < 4; ++j) {
        int d = d0 + j;
        float v = kt[j];
        if (d >= 1 && d <= 5) v += M[o * 5 + (d - 1)];   // AR taps
        KT[o * 512 + d] = f2bf(v);
        G[d * 512 + o]  = gg[j];
    }
}

// K3: per batch, Y[b] = Toep(x[b]) @ K + G.  Tile 128x128, 4 waves of 64x64.
// MFMA operands SWAPPED: acc = mfma(b_frag, a_frag, acc) so D rows map to o,
// cols to t -> each lane holds float4 contiguous along o (vector epilogue).
__global__ __launch_bounds__(256, 3) void k_main(const float* __restrict__ x,
                                                 const unsigned short* __restrict__ KT,
                                                 const float* __restrict__ G,
                                                 float* __restrict__ out) {
    __shared__ short8v xoct[1024];   // xoct[j] = {xe[j], ..., xe[j+7]}, 16 KB

    const int b   = blockIdx.z;
    const int bt0 = blockIdx.y * 128;
    const int bo0 = blockIdx.x * 128;
    const int tid = threadIdx.x;
    const float* xb = x + b * 512;

    // build xe-octet table straight from global: xe[i] = (i<512) ? x[511-i] : 0
    #pragma unroll
    for (int q = 0; q < 4; ++q) {
        int e = tid * 4 + q;
        short8v v;
        #pragma unroll
        for (int jj = 0; jj < 8; ++jj) {
            int i = e + jj;
            float f = (i < 512) ? xb[511 - i] : 0.0f;
            v[jj] = (short)f2bf(f);
        }
        xoct[e] = v;
    }
    __syncthreads();

    const int lane = tid & 63;
    const int w    = tid >> 6;
    const int wm   = w >> 1, wn = w & 1;
    const int t0w  = bt0 + wm * 64;
    const int o0w  = bo0 + wn * 64;
    const int lrow = lane & 15;
    const int g    = lane >> 4;

    float4v acc[4][4];
    #pragma unroll
    for (int mi = 0; mi < 4; ++mi)
        #pragma unroll
        for (int ni = 0; ni < 4; ++ni)
            acc[mi][ni] = (float4v)(0.0f);

    int aent[4];
    const unsigned short* bptr[4];
    #pragma unroll
    for (int i = 0; i < 4; ++i) {
        aent[i] = 511 - (t0w + i * 16 + lrow) + g * 8;            // in [0,535]
        bptr[i] = KT + (o0w + i * 16 + lrow) * 512 + g * 8;       // k-contiguous
    }

    // software-pipelined K loop: prefetch ks+1 while doing MFMAs of ks
    short8v a_c[4], b_c[4];
    #pragma unroll
    for (int i = 0; i < 4; ++i) a_c[i] = xoct[aent[i]];
    #pragma unroll
    for (int i = 0; i < 4; ++i) b_c[i] = *(const short8v*)(bptr[i]);

    #pragma unroll
    for (int ks = 0; ks < 16; ++ks) {
        short8v a_n[4], b_n[4];
        if (ks < 15) {
            #pragma unroll
            for (int i = 0; i < 4; ++i)
                b_n[i] = *(const short8v*)(bptr[i] + (ks + 1) * 32);
            #pragma unroll
            for (int i = 0; i < 4; ++i)
                a_n[i] = xoct[aent[i] + (ks + 1) * 32];
        }
        #pragma unroll
        for (int mi = 0; mi < 4; ++mi)
            #pragma unroll
            for (int ni = 0; ni < 4; ++ni)
                acc[mi][ni] = __builtin_amdgcn_mfma_f32_16x16x32_bf16(
                    b_c[ni], a_c[mi], acc[mi][ni], 0, 0, 0);
        if (ks < 15) {
            #pragma unroll
            for (int i = 0; i < 4; ++i) { a_c[i] = a_n[i]; b_c[i] = b_n[i]; }
        }
    }

    // epilogue (swapped D layout): lane holds o = o0w+ni*16+g*4+r (r contiguous),
    // t = t0w+mi*16+lrow  -> float4 loads of G, float4 nontemporal stores.
    float* outb = out + (size_t)b * 512 * 512;
    #pragma unroll
    for (int mi = 0; mi < 4; ++mi) {
        const int t = t0w + mi * 16 + lrow;
        const float* gp = G + t * 512;
        float* op = outb + t * 512;
        #pragma unroll
        for (int ni = 0; ni < 4; ++ni) {
            const int o = o0w + ni * 16 + g * 4;
            float4v gv = *(const float4v*)(gp + o);
            float4v v = acc[mi][ni] + gv;
            __builtin_nontemporal_store(v, (float4v*)(op + o));
        }
    }
}

extern "C" void kernel_launch(void* const* d_in, const int* in_sizes, int n_in,
                              void* d_out, int out_size, void* d_ws, size_t ws_size,
                              hipStream_t stream) {
    const float* x  = (const float*)d_in[0];   // [256,512,1]
    const float* A  = (const float*)d_in[1];   // [512]
    const float* B  = (const float*)d_in[2];   // [1,512]
    const float* C  = (const float*)d_in[3];   // [512,512]
    const float* M  = (const float*)d_in[4];   // [512,1,5]
    const float* h0 = (const float*)d_in[5];   // [512]
    float* out = (float*)d_out;

    char* ws = (char*)d_ws;
    float*          PBT = (float*)ws;                              // 1 MB
    float*          PHT = (float*)(ws + (1u << 20));               // 1 MB
    unsigned short* KT  = (unsigned short*)(ws + (2u << 20));      // 512 KB
    float*          G   = (float*)(ws + (2u << 20) + (1u << 19));  // 1 MB

    k_tables<<<512, 512, 0, stream>>>(A, B, h0, PBT, PHT);
    k_ktg<<<dim3(128, 2), 256, 0, stream>>>(C, M, PBT, PHT, KT, G);
    k_main<<<dim3(4, 4, 256), 256, 0, stream>>>(x, KT, G, out);
}

// Round 3
// 167.693 us; speedup vs baseline: 1.6161x; 1.5793x over previous
//
#include <hip/hip_runtime.h>

// LDS forward collapsed to causal conv:
//   y[b,t,o] = sum_{d<=t} x[b,t-d] * K[d,o] + G[t,o]
//   K[d,o] = sum_s C[s,o] A[s]^d B[s]  (+ M[o,0,d-1] for d in 1..5)
//   G[t,o] = sum_s C[s,o] A[s]^{t+1} h0[s]
//
// k_main: KT held fully in registers per wave (32o x 512k = 128 VGPR);
// Toeplitz A-frags from LDS with diagonal reuse: frag(mi,ks) depends only on
// j = 2*ks - mi  ->  2 new ds_reads per k-step, rolling window of 8.

typedef __attribute__((ext_vector_type(8))) short short8v;
typedef __attribute__((ext_vector_type(4))) float float4v;

static __device__ __forceinline__ unsigned short f2bf(float f) {
    union { float f; unsigned int u; } x; x.f = f;
    unsigned int r = x.u + 0x7fffu + ((x.u >> 16) & 1u);  // RNE
    return (unsigned short)(r >> 16);
}

// K1: PBT[s][d] = A[s]^d * B[s];  PHT[s][d] = A[s]^(d+1) * h0[s]
__global__ __launch_bounds__(512) void k_tables(const float* __restrict__ A,
                                                const float* __restrict__ B,
                                                const float* __restrict__ h0,
                                                float* __restrict__ PBT,
                                                float* __restrict__ PHT) {
    int s = blockIdx.x;
    int d = threadIdx.x;
    float a = A[s];
    float r = 1.0f, base = a;
    #pragma unroll
    for (int bit = 0; bit < 9; ++bit) {
        if (d & (1 << bit)) r *= base;
        base *= base;
    }
    PBT[s * 512 + d] = r * B[s];
    PHT[s * 512 + d] = r * a * h0[s];
}

// K2: KT[o][d] (bf16, o-major) and G[t][o] (f32).
// 1024 blocks x 4 waves: each wave reduces a 128-s chunk, LDS-reduce across.
__global__ __launch_bounds__(256) void k_ktg(const float* __restrict__ C,
                                             const float* __restrict__ M,
                                             const float* __restrict__ PBT,
                                             const float* __restrict__ PHT,
                                             unsigned short* __restrict__ KT,
                                             float* __restrict__ G) {
    __shared__ float red[4][64][8];
    const int lane = threadIdx.x & 63;
    const int sc   = threadIdx.x >> 6;          // 0..3 s-chunk
    const int o    = blockIdx.y * 64 + lane;
    const int d0   = blockIdx.x * 4;

    float kt[4] = {0.f, 0.f, 0.f, 0.f};
    float gg[4] = {0.f, 0.f, 0.f, 0.f};
    #pragma unroll 4
    for (int si = 0; si < 128; ++si) {
        int s = sc * 128 + si;
        float c = C[s * 512 + o];
        const float* pb = PBT + s * 512 + d0;   // wave-uniform -> scalar loads
        const float* ph = PHT + s * 512 + d0;
        #pragma unroll
        for (int j = 0; j < 4; ++j) {
            kt[j] = fmaf(pb[j], c, kt[j]);
            gg[j] = fmaf(ph[j], c, gg[j]);
        }
    }
    #pragma unroll
    for (int j = 0; j < 4; ++j) {
        red[sc][lane][j]     = kt[j];
        red[sc][lane][j + 4] = gg[j];
    }
    __syncthreads();
    if (sc == 0) {
        #pragma unroll
        for (int j = 0; j < 4; ++j) {
            float v = red[0][lane][j] + red[1][lane][j] + red[2][lane][j] + red[3][lane][j];
            float g = red[0][lane][j+4] + red[1][lane][j+4] + red[2][lane][j+4] + red[3][lane][j+4];
            int d = d0 + j;
            if (d >= 1 && d <= 5) v += M[o * 5 + (d - 1)];   // AR taps
            KT[o * 512 + d] = f2bf(v);
            G[d * 512 + o]  = g;
        }
    }
}

// K3: block = 128t x 256o for one batch; 8 waves of 128t x 32o.
// grid (2 o-halves, 4 t-quarters, 256 b), 512 threads.
__global__ __launch_bounds__(512, 2) void k_main(const float* __restrict__ x,
                                                 const unsigned short* __restrict__ KT,
                                                 const float* __restrict__ G,
                                                 float* __restrict__ out) {
    __shared__ short8v xoct[1024];   // xoct[j] = {xe[j],..,xe[j+7]}, xe[i]=x[511-i]

    const int b   = blockIdx.z;
    const int bt0 = blockIdx.y * 128;
    const int bo0 = blockIdx.x * 256;
    const int tid = threadIdx.x;
    const float* xb = x + b * 512;

    // build reversed-octet table (1024 entries, 2 per thread)
    #pragma unroll
    for (int q = 0; q < 2; ++q) {
        int e = tid * 2 + q;
        short8v v;
        #pragma unroll
        for (int jj = 0; jj < 8; ++jj) {
            int i = e + jj;
            float f = (i < 512) ? xb[511 - i] : 0.0f;
            v[jj] = (short)f2bf(f);
        }
        xoct[e] = v;
    }
    __syncthreads();

    const int lane = tid & 63;
    const int w    = tid >> 6;          // 0..7
    const int o0w  = bo0 + w * 32;
    const int lrow = lane & 15;
    const int g    = lane >> 4;

    // preload this wave's full KT slice: 2 ni x 16 ks x 16B = 128 VGPR
    short8v bfr[2][16];
    #pragma unroll
    for (int ni = 0; ni < 2; ++ni) {
        const unsigned short* bp = KT + (o0w + ni * 16 + lrow) * 512 + g * 8;
        #pragma unroll
        for (int ks = 0; ks < 16; ++ks)
            bfr[ni][ks] = *(const short8v*)(bp + ks * 32);
    }

    float4v acc[8][2];
    #pragma unroll
    for (int mi = 0; mi < 8; ++mi)
        #pragma unroll
        for (int ni = 0; ni < 2; ++ni)
            acc[mi][ni] = (float4v)(0.0f);

    // A-frag rolling window: frag j at xoct[E0 + 16*j], j = 2*ks - mi
    const int E0 = 511 - bt0 - lrow + g * 8;    // in [112, 535]
    short8v aw[8];
    #pragma unroll
    for (int j = -7; j <= 0; ++j)
        aw[j & 7] = xoct[E0 + 16 * j];

    #pragma unroll
    for (int ks = 0; ks < 16; ++ks) {
        // consume oldest first (mi=7,6), then refill their slots for ks+1
        #pragma unroll
        for (int mi = 7; mi >= 6; --mi)
            #pragma unroll
            for (int ni = 0; ni < 2; ++ni)
                acc[mi][ni] = __builtin_amdgcn_mfma_f32_16x16x32_bf16(
                    bfr[ni][ks], aw[(2 * ks - mi) & 7], acc[mi][ni], 0, 0, 0);
        if (ks < 15) {
            aw[(2 * ks + 1) & 7] = xoct[E0 + 16 * (2 * ks + 1)];
            aw[(2 * ks + 2) & 7] = xoct[E0 + 16 * (2 * ks + 2)];
        }
        #pragma unroll
        for (int mi = 5; mi >= 0; --mi)
            #pragma unroll
            for (int ni = 0; ni < 2; ++ni)
                acc[mi][ni] = __builtin_amdgcn_mfma_f32_16x16x32_bf16(
                    bfr[ni][ks], aw[(2 * ks - mi) & 7], acc[mi][ni], 0, 0, 0);
    }

    // epilogue: D row=o (g*4+r contiguous), col=t (lrow). float4 G-load + store.
    float* outb = out + (size_t)b * 512 * 512;
    #pragma unroll
    for (int mi = 0; mi < 8; ++mi) {
        const int t = bt0 + mi * 16 + lrow;
        const float* gp = G + t * 512;
        float* op = outb + t * 512;
        #pragma unroll
        for (int ni = 0; ni < 2; ++ni) {
            const int o = o0w + ni * 16 + g * 4;
            float4v gv = *(const float4v*)(gp + o);
            float4v v = acc[mi][ni] + gv;
            *(float4v*)(op + o) = v;
        }
    }
}

extern "C" void kernel_launch(void* const* d_in, const int* in_sizes, int n_in,
                              void* d_out, int out_size, void* d_ws, size_t ws_size,
                              hipStream_t stream) {
    const float* x  = (const float*)d_in[0];   // [256,512,1]
    const float* A  = (const float*)d_in[1];   // [512]
    const float* B  = (const float*)d_in[2];   // [1,512]
    const float* C  = (const float*)d_in[3];   // [512,512]
    const float* M  = (const float*)d_in[4];   // [512,1,5]
    const float* h0 = (const float*)d_in[5];   // [512]
    float* out = (float*)d_out;

    char* ws = (char*)d_ws;
    float*          PBT = (float*)ws;                              // 1 MB
    float*          PHT = (float*)(ws + (1u << 20));               // 1 MB
    unsigned short* KT  = (unsigned short*)(ws + (2u << 20));      // 512 KB
    float*          G   = (float*)(ws + (2u << 20) + (1u << 19));  // 1 MB

    k_tables<<<512, 512, 0, stream>>>(A, B, h0, PBT, PHT);
    k_ktg<<<dim3(128, 8), 256, 0, stream>>>(C, M, PBT, PHT, KT, G);
    k_main<<<dim3(2, 4, 256), 512, 0, stream>>>(x, KT, G, out);
}

// Round 4
// 158.509 us; speedup vs baseline: 1.7098x; 1.0579x over previous
//
#include <hip/hip_runtime.h>

// LDS forward collapsed to causal conv:
//   y[b,t,o] = sum_{d<=t} x[b,t-d] * K[d,o] + G[t,o]
//   K[d,o] = sum_s C[s,o] A[s]^d B[s]  (+ M[o,0,d-1] for d in 1..5)
//   G[t,o] = sum_s C[s,o] A[s]^{t+1} h0[s]
//
// k_main: 256 blocks (1/CU), each owns a 128t x 256o tile and loops over 8
// batches, keeping its KT register slice (32o x 512k per wave) resident.
// Toeplitz A-frags from LDS with diagonal reuse (j = 2*ks - mi -> 2 ds_reads
// per k-step). Per-batch x staged from a precomputed octet table (XOCT) via
// double-buffered LDS: loads issued before the MFMA loop, written after.

typedef __attribute__((ext_vector_type(8))) short short8v;
typedef __attribute__((ext_vector_type(4))) float float4v;

#define NB 8   // batches per k_main block

static __device__ __forceinline__ unsigned short f2bf(float f) {
    union { float f; unsigned int u; } x; x.f = f;
    unsigned int r = x.u + 0x7fffu + ((x.u >> 16) & 1u);  // RNE
    return (unsigned short)(r >> 16);
}

// K1: PBT[s][d] = A[s]^d * B[s];  PHT[s][d] = A[s]^(d+1) * h0[s]
__global__ __launch_bounds__(512) void k_tables(const float* __restrict__ A,
                                                const float* __restrict__ B,
                                                const float* __restrict__ h0,
                                                float* __restrict__ PBT,
                                                float* __restrict__ PHT) {
    int s = blockIdx.x;
    int d = threadIdx.x;
    float a = A[s];
    float r = 1.0f, base = a;
    #pragma unroll
    for (int bit = 0; bit < 9; ++bit) {
        if (d & (1 << bit)) r *= base;
        base *= base;
    }
    PBT[s * 512 + d] = r * B[s];
    PHT[s * 512 + d] = r * a * h0[s];
}

// K1b: XOCT[b][e] = { xe[e], .., xe[e+7] },  xe[i] = bf16(x[b][511-i]), 0 for i>=512
__global__ __launch_bounds__(256) void k_xprep(const float* __restrict__ x,
                                               short8v* __restrict__ XOCT) {
    __shared__ unsigned short xs[512];
    const int b = blockIdx.x, tid = threadIdx.x;
    #pragma unroll
    for (int q = 0; q < 2; ++q) {
        int i = tid * 2 + q;
        xs[i] = f2bf(x[b * 512 + 511 - i]);
    }
    __syncthreads();
    #pragma unroll
    for (int q = 0; q < 4; ++q) {
        int e = tid * 4 + q;
        short8v v;
        #pragma unroll
        for (int jj = 0; jj < 8; ++jj) {
            int i = e + jj;
            v[jj] = (i < 512) ? (short)xs[i] : (short)0;
        }
        XOCT[b * 1024 + e] = v;
    }
}

// K2: KT[o][d] (bf16, o-major) and G[t][o] (f32).
__global__ __launch_bounds__(256) void k_ktg(const float* __restrict__ C,
                                             const float* __restrict__ M,
                                             const float* __restrict__ PBT,
                                             const float* __restrict__ PHT,
                                             unsigned short* __restrict__ KT,
                                             float* __restrict__ G) {
    __shared__ float red[4][64][8];
    const int lane = threadIdx.x & 63;
    const int sc   = threadIdx.x >> 6;          // 0..3 s-chunk
    const int o    = blockIdx.y * 64 + lane;
    const int d0   = blockIdx.x * 4;

    float kt[4] = {0.f, 0.f, 0.f, 0.f};
    float gg[4] = {0.f, 0.f, 0.f, 0.f};
    #pragma unroll 4
    for (int si = 0; si < 128; ++si) {
        int s = sc * 128 + si;
        float c = C[s * 512 + o];
        const float* pb = PBT + s * 512 + d0;   // wave-uniform -> scalar loads
        const float* ph = PHT + s * 512 + d0;
        #pragma unroll
        for (int j = 0; j < 4; ++j) {
            kt[j] = fmaf(pb[j], c, kt[j]);
            gg[j] = fmaf(ph[j], c, gg[j]);
        }
    }
    #pragma unroll
    for (int j = 0; j < 4; ++j) {
        red[sc][lane][j]     = kt[j];
        red[sc][lane][j + 4] = gg[j];
    }
    __syncthreads();
    if (sc == 0) {
        #pragma unroll
        for (int j = 0; j < 4; ++j) {
            float v = red[0][lane][j] + red[1][lane][j] + red[2][lane][j] + red[3][lane][j];
            float g = red[0][lane][j+4] + red[1][lane][j+4] + red[2][lane][j+4] + red[3][lane][j+4];
            int d = d0 + j;
            if (d >= 1 && d <= 5) v += M[o * 5 + (d - 1)];   // AR taps
            KT[o * 512 + d] = f2bf(v);
            G[d * 512 + o]  = g;
        }
    }
}

// K3: block = 128t x 256o, 8 waves of 128t x 32o, NB batches per block.
// grid (2 o-halves, 4 t-quarters, 256/NB batch-groups), 512 threads.
__global__ __launch_bounds__(512, 2) void k_main(const short8v* __restrict__ XOCT,
                                                 const unsigned short* __restrict__ KT,
                                                 const float* __restrict__ G,
                                                 float* __restrict__ out) {
    __shared__ short8v xbuf[2][1024];   // double-buffered octet table, 32 KB

    const int bt0 = blockIdx.y * 128;
    const int bo0 = blockIdx.x * 256;
    const int b0  = blockIdx.z * NB;
    const int tid = threadIdx.x;

    const int lane = tid & 63;
    const int w    = tid >> 6;          // 0..7
    const int o0w  = bo0 + w * 32;
    const int lrow = lane & 15;
    const int g    = lane >> 4;

    // stage batch b0 into xbuf[0]
    {
        const short8v* src = XOCT + (size_t)b0 * 1024;
        xbuf[0][tid * 2 + 0] = src[tid * 2 + 0];
        xbuf[0][tid * 2 + 1] = src[tid * 2 + 1];
    }

    // preload this wave's full KT slice: 2 ni x 16 ks x 16B = 128 VGPR
    short8v bfr[2][16];
    #pragma unroll
    for (int ni = 0; ni < 2; ++ni) {
        const unsigned short* bp = KT + (o0w + ni * 16 + lrow) * 512 + g * 8;
        #pragma unroll
        for (int ks = 0; ks < 16; ++ks)
            bfr[ni][ks] = *(const short8v*)(bp + ks * 32);
    }

    const int E0 = 511 - bt0 - lrow + g * 8;    // A-frag j at xbuf[p][E0 + 16*j]
    __syncthreads();

    int p = 0;
    for (int bi = 0; bi < NB; ++bi) {
        const int b = b0 + bi;

        // issue next batch's staging loads early (hidden under MFMA loop)
        short8v nx0, nx1;
        if (bi < NB - 1) {
            const short8v* src = XOCT + (size_t)(b + 1) * 1024;
            nx0 = src[tid * 2 + 0];
            nx1 = src[tid * 2 + 1];
        }

        float4v acc[8][2];
        #pragma unroll
        for (int mi = 0; mi < 8; ++mi)
            #pragma unroll
            for (int ni = 0; ni < 2; ++ni)
                acc[mi][ni] = (float4v)(0.0f);

        const short8v* xo = xbuf[p];
        short8v aw[8];
        #pragma unroll
        for (int j = -7; j <= 0; ++j)
            aw[j & 7] = xo[E0 + 16 * j];

        #pragma unroll
        for (int ks = 0; ks < 16; ++ks) {
            #pragma unroll
            for (int mi = 7; mi >= 6; --mi)
                #pragma unroll
                for (int ni = 0; ni < 2; ++ni)
                    acc[mi][ni] = __builtin_amdgcn_mfma_f32_16x16x32_bf16(
                        bfr[ni][ks], aw[(2 * ks - mi) & 7], acc[mi][ni], 0, 0, 0);
            if (ks < 15) {
                aw[(2 * ks + 1) & 7] = xo[E0 + 16 * (2 * ks + 1)];
                aw[(2 * ks + 2) & 7] = xo[E0 + 16 * (2 * ks + 2)];
            }
            #pragma unroll
            for (int mi = 5; mi >= 0; --mi)
                #pragma unroll
                for (int ni = 0; ni < 2; ++ni)
                    acc[mi][ni] = __builtin_amdgcn_mfma_f32_16x16x32_bf16(
                        bfr[ni][ks], aw[(2 * ks - mi) & 7], acc[mi][ni], 0, 0, 0);
        }

        // epilogue: D row = o (g*4+r contiguous), col = t (lrow)
        float* outb = out + (size_t)b * 262144;
        #pragma unroll
        for (int mi = 0; mi < 8; ++mi) {
            const int t = bt0 + mi * 16 + lrow;
            const float* gp = G + t * 512;
            float* op = outb + t * 512;
            #pragma unroll
            for (int ni = 0; ni < 2; ++ni) {
                const int o = o0w + ni * 16 + g * 4;
                float4v gv = *(const float4v*)(gp + o);
                *(float4v*)(op + o) = acc[mi][ni] + gv;
            }
        }

        if (bi < NB - 1) {
            xbuf[p ^ 1][tid * 2 + 0] = nx0;
            xbuf[p ^ 1][tid * 2 + 1] = nx1;
            __syncthreads();
            p ^= 1;
        }
    }
}

extern "C" void kernel_launch(void* const* d_in, const int* in_sizes, int n_in,
                              void* d_out, int out_size, void* d_ws, size_t ws_size,
                              hipStream_t stream) {
    const float* x  = (const float*)d_in[0];   // [256,512,1]
    const float* A  = (const float*)d_in[1];   // [512]
    const float* B  = (const float*)d_in[2];   // [1,512]
    const float* C  = (const float*)d_in[3];   // [512,512]
    const float* M  = (const float*)d_in[4];   // [512,1,5]
    const float* h0 = (const float*)d_in[5];   // [512]
    float* out = (float*)d_out;

    char* ws = (char*)d_ws;
    float*          PBT  = (float*)ws;                              // 1 MB
    float*          PHT  = (float*)(ws + (1u << 20));               // 1 MB
    unsigned short* KT   = (unsigned short*)(ws + (2u << 20));      // 512 KB
    float*          G    = (float*)(ws + (2u << 20) + (1u << 19));  // 1 MB
    short8v*        XOCT = (short8v*)(ws + (3u << 20) + (1u << 19));// 4 MB

    k_tables<<<512, 512, 0, stream>>>(A, B, h0, PBT, PHT);
    k_xprep<<<256, 256, 0, stream>>>(x, XOCT);
    k_ktg<<<dim3(128, 8), 256, 0, stream>>>(C, M, PBT, PHT, KT, G);
    k_main<<<dim3(2, 4, 256 / NB), 512, 0, stream>>>(XOCT, KT, G, out);
}

// Round 5
// 124.409 us; speedup vs baseline: 2.1784x; 1.2741x over previous
//
#include <hip/hip_runtime.h>

// LDS forward collapsed to causal conv:
//   y[b,t,o] = sum_{d<=t} x[b,t-d] * K[d,o] + G[t,o]
//   K[d,o] = sum_s C[s,o] A[s]^d B[s]  (+ M[o,0,d-1] for d in 1..5)
//   G[t,o] = sum_s C[s,o] A[s]^{t+1} h0[s]
//
// k_main: 256 blocks (1/CU), block = 128t x 128o, 8 waves of 64t x 32o,
// NB=16 batches per block. KT register-resident (32o x 512k = 128 VGPR/wave).
// Toeplitz A-frags from padded LDS octet table, diagonal reuse (j = 2*ks-mi,
// 2 ds_reads/k-step). Raw s_barrier + lgkmcnt-only wait so global stores
// drain across batch boundaries (no vmcnt(0) serialization).

typedef __attribute__((ext_vector_type(8))) short short8v;
typedef __attribute__((ext_vector_type(4))) float float4v;

#define NB 16   // batches per k_main block

static __device__ __forceinline__ unsigned short f2bf(float f) {
    union { float f; unsigned int u; } x; x.f = f;
    unsigned int r = x.u + 0x7fffu + ((x.u >> 16) & 1u);  // RNE
    return (unsigned short)(r >> 16);
}

// K1: PBT[s][d] = A[s]^d * B[s];  PHT[s][d] = A[s]^(d+1) * h0[s]
__global__ __launch_bounds__(512) void k_tables(const float* __restrict__ A,
                                                const float* __restrict__ B,
                                                const float* __restrict__ h0,
                                                float* __restrict__ PBT,
                                                float* __restrict__ PHT) {
    int s = blockIdx.x;
    int d = threadIdx.x;
    float a = A[s];
    float r = 1.0f, base = a;
    #pragma unroll
    for (int bit = 0; bit < 9; ++bit) {
        if (d & (1 << bit)) r *= base;
        base *= base;
    }
    PBT[s * 512 + d] = r * B[s];
    PHT[s * 512 + d] = r * a * h0[s];
}

// K1b: XOCT[b][e] = { xe[e], .., xe[e+7] },  xe[i] = bf16(x[b][511-i]), 0 for i>=512
__global__ __launch_bounds__(256) void k_xprep(const float* __restrict__ x,
                                               short8v* __restrict__ XOCT) {
    __shared__ unsigned short xs[512];
    const int b = blockIdx.x, tid = threadIdx.x;
    #pragma unroll
    for (int q = 0; q < 2; ++q) {
        int i = tid * 2 + q;
        xs[i] = f2bf(x[b * 512 + 511 - i]);
    }
    __syncthreads();
    #pragma unroll
    for (int q = 0; q < 4; ++q) {
        int e = tid * 4 + q;
        short8v v;
        #pragma unroll
        for (int jj = 0; jj < 8; ++jj) {
            int i = e + jj;
            v[jj] = (i < 512) ? (short)xs[i] : (short)0;
        }
        XOCT[b * 1024 + e] = v;
    }
}

// K2: KT[o][d] (bf16, o-major) and G[t][o] (f32).
__global__ __launch_bounds__(256) void k_ktg(const float* __restrict__ C,
                                             const float* __restrict__ M,
                                             const float* __restrict__ PBT,
                                             const float* __restrict__ PHT,
                                             unsigned short* __restrict__ KT,
                                             float* __restrict__ G) {
    __shared__ float red[4][64][8];
    const int lane = threadIdx.x & 63;
    const int sc   = threadIdx.x >> 6;          // 0..3 s-chunk
    const int o    = blockIdx.y * 64 + lane;
    const int d0   = blockIdx.x * 4;

    float kt[4] = {0.f, 0.f, 0.f, 0.f};
    float gg[4] = {0.f, 0.f, 0.f, 0.f};
    #pragma unroll 4
    for (int si = 0; si < 128; ++si) {
        int s = sc * 128 + si;
        float c = C[s * 512 + o];
        const float* pb = PBT + s * 512 + d0;   // wave-uniform -> scalar loads
        const float* ph = PHT + s * 512 + d0;
        #pragma unroll
        for (int j = 0; j < 4; ++j) {
            kt[j] = fmaf(pb[j], c, kt[j]);
            gg[j] = fmaf(ph[j], c, gg[j]);
        }
    }
    #pragma unroll
    for (int j = 0; j < 4; ++j) {
        red[sc][lane][j]     = kt[j];
        red[sc][lane][j + 4] = gg[j];
    }
    __syncthreads();
    if (sc == 0) {
        #pragma unroll
        for (int j = 0; j < 4; ++j) {
            float v = red[0][lane][j] + red[1][lane][j] + red[2][lane][j] + red[3][lane][j];
            float g = red[0][lane][j+4] + red[1][lane][j+4] + red[2][lane][j+4] + red[3][lane][j+4];
            int d = d0 + j;
            if (d >= 1 && d <= 5) v += M[o * 5 + (d - 1)];   // AR taps
            KT[o * 512 + d] = f2bf(v);
            G[d * 512 + o]  = g;
        }
    }
}

// K3: grid (4 o-blocks, 4 t-blocks, 16 batch-groups) = 256 blocks, 512 thr.
__global__ __launch_bounds__(512, 2) void k_main(const short8v* __restrict__ XOCT,
                                                 const unsigned short* __restrict__ KT,
                                                 const float* __restrict__ G,
                                                 float* __restrict__ out) {
    // padded octet table: entry e lives at index e + (e>>3)  (breaks 4-way
    // bank aliasing of the g-dimension). 1151 slots -> 1152, 2 buffers = 36 KB.
    __shared__ short8v xbuf[2][1152];

    const int bt0 = blockIdx.y * 128;
    const int bo0 = blockIdx.x * 128;
    const int b0  = blockIdx.z * NB;
    const int tid = threadIdx.x;
    const int lane = tid & 63;
    const int w    = tid >> 6;          // 0..7
    const int wm   = w >> 2, wn = w & 3;
    const int t0w  = bt0 + wm * 64;
    const int o0w  = bo0 + wn * 32;
    const int lrow = lane & 15;
    const int g    = lane >> 4;
    const int idx0 = tid + (tid >> 3);  // padded slot for entry e = tid

    // issue batch-0 staging loads FIRST (oldest in vmcnt order), then KT
    // preload; the ds_write below then only waits vmcnt(32).
    const short8v* src0 = XOCT + (size_t)b0 * 1024;
    short8v nxa = src0[tid];
    short8v nxb = src0[tid + 512];

    // KT register slice: 2 ni x 16 ks x 16B = 128 VGPR, issued in ks order
    short8v bfr[2][16];
    #pragma unroll
    for (int ni = 0; ni < 2; ++ni) {
        const unsigned short* bp = KT + (o0w + ni * 16 + lrow) * 512 + g * 8;
        #pragma unroll
        for (int ks = 0; ks < 16; ++ks)
            bfr[ni][ks] = *(const short8v*)(bp + ks * 32);
    }

    xbuf[0][idx0]       = nxa;
    xbuf[0][idx0 + 576] = nxb;      // entry tid+512 -> +512+64 padded
    asm volatile("s_waitcnt lgkmcnt(0)" ::: "memory");
    __builtin_amdgcn_s_barrier();

    const int E0 = 511 - t0w - lrow + g * 8;   // frag j at entry E0 + 16*j

    int p = 0;
    for (int bi = 0; bi < NB; ++bi) {
        const int b = b0 + bi;

        // issue next batch's staging loads early (drain under MFMA loop)
        if (bi < NB - 1) {
            const short8v* src = XOCT + (size_t)(b + 1) * 1024;
            nxa = src[tid];
            nxb = src[tid + 512];
        }

        float4v acc[4][2];
        #pragma unroll
        for (int mi = 0; mi < 4; ++mi)
            #pragma unroll
            for (int ni = 0; ni < 2; ++ni)
                acc[mi][ni] = (float4v)(0.0f);

        const short8v* xo = xbuf[p];
        short8v aw[8];
        #pragma unroll
        for (int j = -3; j <= 0; ++j) {
            int e = E0 + 16 * j;
            aw[j & 7] = xo[e + (e >> 3)];
        }

        #pragma unroll
        for (int ks = 0; ks < 16; ++ks) {
            #pragma unroll
            for (int mi = 3; mi >= 2; --mi)
                #pragma unroll
                for (int ni = 0; ni < 2; ++ni)
                    acc[mi][ni] = __builtin_amdgcn_mfma_f32_16x16x32_bf16(
                        bfr[ni][ks], aw[(2 * ks - mi) & 7], acc[mi][ni], 0, 0, 0);
            if (ks < 15) {
                int e1 = E0 + 16 * (2 * ks + 1);
                int e2 = E0 + 16 * (2 * ks + 2);
                aw[(2 * ks + 1) & 7] = xo[e1 + (e1 >> 3)];
                aw[(2 * ks + 2) & 7] = xo[e2 + (e2 >> 3)];
            }
            #pragma unroll
            for (int mi = 1; mi >= 0; --mi)
                #pragma unroll
                for (int ni = 0; ni < 2; ++ni)
                    acc[mi][ni] = __builtin_amdgcn_mfma_f32_16x16x32_bf16(
                        bfr[ni][ks], aw[(2 * ks - mi) & 7], acc[mi][ni], 0, 0, 0);
        }

        // epilogue: D row = o (g*4+r contiguous), col = t (lrow)
        float* outb = out + (size_t)b * 262144;
        #pragma unroll
        for (int mi = 0; mi < 4; ++mi) {
            const int t = t0w + mi * 16 + lrow;
            const float* gp = G + t * 512;
            float* op = outb + t * 512;
            #pragma unroll
            for (int ni = 0; ni < 2; ++ni) {
                const int o = o0w + ni * 16 + g * 4;
                float4v gv = *(const float4v*)(gp + o);
                *(float4v*)(op + o) = acc[mi][ni] + gv;
            }
        }

        // write next batch's buffer; raw barrier with lgkm-only wait so the
        // epilogue's global stores keep draining across the boundary.
        if (bi < NB - 1) {
            short8v* xw = xbuf[p ^ 1];
            xw[idx0]       = nxa;
            xw[idx0 + 576] = nxb;
            asm volatile("s_waitcnt lgkmcnt(0)" ::: "memory");
            __builtin_amdgcn_s_barrier();
            p ^= 1;
        }
    }
}

extern "C" void kernel_launch(void* const* d_in, const int* in_sizes, int n_in,
                              void* d_out, int out_size, void* d_ws, size_t ws_size,
                              hipStream_t stream) {
    const float* x  = (const float*)d_in[0];   // [256,512,1]
    const float* A  = (const float*)d_in[1];   // [512]
    const float* B  = (const float*)d_in[2];   // [1,512]
    const float* C  = (const float*)d_in[3];   // [512,512]
    const float* M  = (const float*)d_in[4];   // [512,1,5]
    const float* h0 = (const float*)d_in[5];   // [512]
    float* out = (float*)d_out;

    char* ws = (char*)d_ws;
    float*          PBT  = (float*)ws;                              // 1 MB
    float*          PHT  = (float*)(ws + (1u << 20));               // 1 MB
    unsigned short* KT   = (unsigned short*)(ws + (2u << 20));      // 512 KB
    float*          G    = (float*)(ws + (2u << 20) + (1u << 19));  // 1 MB
    short8v*        XOCT = (short8v*)(ws + (3u << 20) + (1u << 19));// 4 MB

    k_tables<<<512, 512, 0, stream>>>(A, B, h0, PBT, PHT);
    k_xprep<<<256, 256, 0, stream>>>(x, XOCT);
    k_ktg<<<dim3(128, 8), 256, 0, stream>>>(C, M, PBT, PHT, KT, G);
    k_main<<<dim3(4, 4, 256 / NB), 512, 0, stream>>>(XOCT, KT, G, out);
}

// Round 6
// 124.384 us; speedup vs baseline: 2.1789x; 1.0002x over previous
//
#include <hip/hip_runtime.h>

// LDS forward collapsed to causal conv:
//   y[b,t,o] = sum_{d<=t} x[b,t-d] * K[d,o] + G[t,o]
//   K[d,o] = sum_s C[s,o] A[s]^d B[s]  (+ M[o,0,d-1] for d in 1..5)
//   G[t,o] = sum_s C[s,o] A[s]^{t+1} h0[s]
//
// k_main R6: 256 blocks (1/CU), block = 128t x 64o, 8 waves of 64t x 16o,
// NB=32 batches/block. KT slice in XOR-swizzled LDS (64 KB) -> low VGPR
// pressure (~120), no spill. G batch-invariant -> 16 regs. Toeplitz A-frags
// from sigma-padded LDS octet table (diagonal reuse, 2 ds_reads/k-step).
// Raw s_barrier + lgkmcnt-only wait so stores drain across batches.

typedef __attribute__((ext_vector_type(8))) short short8v;
typedef __attribute__((ext_vector_type(4))) float float4v;

#define NB 32
#define SIG(e) ((e) + ((e) >> 3))   // pad: entry e -> slot e + e/8

static __device__ __forceinline__ unsigned short f2bf(float f) {
    union { float f; unsigned int u; } x; x.f = f;
    unsigned int r = x.u + 0x7fffu + ((x.u >> 16) & 1u);  // RNE
    return (unsigned short)(r >> 16);
}

// K1: PBT[s][d] = A[s]^d * B[s];  PHT[s][d] = A[s]^(d+1) * h0[s]
__global__ __launch_bounds__(512) void k_tables(const float* __restrict__ A,
                                                const float* __restrict__ B,
                                                const float* __restrict__ h0,
                                                float* __restrict__ PBT,
                                                float* __restrict__ PHT) {
    int s = blockIdx.x;
    int d = threadIdx.x;
    float a = A[s];
    float r = 1.0f, base = a;
    #pragma unroll
    for (int bit = 0; bit < 9; ++bit) {
        if (d & (1 << bit)) r *= base;
        base *= base;
    }
    PBT[s * 512 + d] = r * B[s];
    PHT[s * 512 + d] = r * a * h0[s];
}

// K1b: XS[b][SIG(e)] = octet(e) of reversed x; unused slots zeroed.
// stride 1216 slots per batch.
__global__ __launch_bounds__(256) void k_xprep(const float* __restrict__ x,
                                               short8v* __restrict__ XS) {
    __shared__ unsigned short xs[512];
    const int b = blockIdx.x, tid = threadIdx.x;
    #pragma unroll
    for (int q = 0; q < 2; ++q) {
        int i = tid * 2 + q;
        xs[i] = f2bf(x[b * 512 + 511 - i]);
    }
    __syncthreads();
    short8v* dst = XS + (size_t)b * 1216;
    for (int s = tid; s < 1216; s += 256) {
        if (s % 9 == 8 || s > 1150) dst[s] = (short8v)(short)0;
    }
    #pragma unroll
    for (int q = 0; q < 4; ++q) {
        int e = tid * 4 + q;
        short8v v;
        #pragma unroll
        for (int jj = 0; jj < 8; ++jj) {
            int i = e + jj;
            v[jj] = (i < 512) ? (short)xs[i] : (short)0;
        }
        dst[SIG(e)] = v;
    }
}

// K2: KT[o][d] (bf16, o-major) and G[t][o] (f32).
__global__ __launch_bounds__(256) void k_ktg(const float* __restrict__ C,
                                             const float* __restrict__ M,
                                             const float* __restrict__ PBT,
                                             const float* __restrict__ PHT,
                                             unsigned short* __restrict__ KT,
                                             float* __restrict__ G) {
    __shared__ float red[4][64][8];
    const int lane = threadIdx.x & 63;
    const int sc   = threadIdx.x >> 6;          // 0..3 s-chunk
    const int o    = blockIdx.y * 64 + lane;
    const int d0   = blockIdx.x * 4;

    float kt[4] = {0.f, 0.f, 0.f, 0.f};
    float gg[4] = {0.f, 0.f, 0.f, 0.f};
    #pragma unroll 4
    for (int si = 0; si < 128; ++si) {
        int s = sc * 128 + si;
        float c = C[s * 512 + o];
        const float* pb = PBT + s * 512 + d0;   // wave-uniform -> scalar loads
        const float* ph = PHT + s * 512 + d0;
        #pragma unroll
        for (int j = 0; j < 4; ++j) {
            kt[j] = fmaf(pb[j], c, kt[j]);
            gg[j] = fmaf(ph[j], c, gg[j]);
        }
    }
    #pragma unroll
    for (int j = 0; j < 4; ++j) {
        red[sc][lane][j]     = kt[j];
        red[sc][lane][j + 4] = gg[j];
    }
    __syncthreads();
    if (sc == 0) {
        #pragma unroll
        for (int j = 0; j < 4; ++j) {
            float v = red[0][lane][j] + red[1][lane][j] + red[2][lane][j] + red[3][lane][j];
            float g = red[0][lane][j+4] + red[1][lane][j+4] + red[2][lane][j+4] + red[3][lane][j+4];
            int d = d0 + j;
            if (d >= 1 && d <= 5) v += M[o * 5 + (d - 1)];   // AR taps
            KT[o * 512 + d] = f2bf(v);
            G[d * 512 + o]  = g;
        }
    }
}

// K3: grid (8 o-blocks, 4 t-blocks, 8 batch-groups) = 256 blocks, 512 thr.
__global__ __launch_bounds__(512, 2) void k_main(const short8v* __restrict__ XS,
                                                 const unsigned short* __restrict__ KT,
                                                 const float* __restrict__ G,
                                                 float* __restrict__ out) {
    __shared__ short8v kt_lds[4096];      // 64 KB, XOR-swizzled [o][k]
    __shared__ short8v xbuf[2][1216];     // 38 KB, sigma-padded octet tables

    const int bo0 = blockIdx.x * 64;
    const int bt0 = blockIdx.y * 128;
    const int b0  = blockIdx.z * NB;
    const int tid = threadIdx.x;
    const int lane = tid & 63;
    const int w    = tid >> 6;
    const int wm   = w >> 2, wn = w & 3;
    const int t0w  = bt0 + wm * 64;
    const int lrow = lane & 15;
    const int g    = lane >> 4;

    // ---- prologue: issue all loads, then write LDS, one sync ----
    const short8v* s0 = XS + (size_t)b0 * 1216;
    short8v x0 = s0[tid], x1 = s0[tid + 512], x2;
    if (tid < 192) x2 = s0[tid + 1024];

    short8v kreg[8];
    #pragma unroll
    for (int r = 0; r < 8; ++r) {
        int c = tid + r * 512;
        int ol = c >> 6, cc = c & 63;
        kreg[r] = *(const short8v*)(KT + (bo0 + ol) * 512 + cc * 8);
    }

    float4v gacc[4];
    #pragma unroll
    for (int mi = 0; mi < 4; ++mi)
        gacc[mi] = *(const float4v*)(G + (t0w + mi * 16 + lrow) * 512
                                       + bo0 + wn * 16 + g * 4);

    char* klw = (char*)kt_lds;
    #pragma unroll
    for (int r = 0; r < 8; ++r) {
        int c = tid + r * 512;
        int ol = c >> 6, cc = c & 63;
        int byte = (ol * 1024 + cc * 16) ^ ((ol & 7) << 4);
        *(short8v*)(klw + byte) = kreg[r];
    }
    xbuf[0][tid] = x0;
    xbuf[0][tid + 512] = x1;
    if (tid < 192) xbuf[0][tid + 1024] = x2;
    __syncthreads();

    const char* kl  = (const char*)kt_lds;
    const int  oby  = (wn * 16 + lrow) * 1024;   // byte base of this wave's o-row
    const int  swz  = (lrow & 7) << 4;
    const int  E0   = 511 - t0w - lrow + g * 8;  // A entry base (frag j at SIG(E0+16j))
    const int  ocol = bo0 + wn * 16 + g * 4;     // output o base (float4)

    int p = 0;
    for (int bi = 0; bi < NB; ++bi) {
        const int b = b0 + bi;

        // issue next batch's staging loads early (drain under MFMA loop)
        short8v nx0, nx1, nx2;
        if (bi + 1 < NB) {
            const short8v* s = XS + (size_t)(b + 1) * 1216;
            nx0 = s[tid];
            nx1 = s[tid + 512];
            if (tid < 192) nx2 = s[tid + 1024];
        }

        const short8v* xo = xbuf[p];

        float4v acc[4];
        #pragma unroll
        for (int mi = 0; mi < 4; ++mi) acc[mi] = (float4v)(0.0f);

        // init windows: B 2-ahead, A frags j=-3..0
        short8v bf[4], aw[8];
        bf[0] = *(const short8v*)(kl + ((oby + 0 * 64 + g * 16) ^ swz));
        bf[1] = *(const short8v*)(kl + ((oby + 1 * 64 + g * 16) ^ swz));
        #pragma unroll
        for (int j = -3; j <= 0; ++j)
            aw[j & 7] = xo[SIG(E0 + 16 * j)];

        #pragma unroll
        for (int ks = 0; ks < 16; ++ks) {
            if (ks < 14)
                bf[(ks + 2) & 3] = *(const short8v*)(kl + ((oby + (ks + 2) * 64 + g * 16) ^ swz));
            acc[3] = __builtin_amdgcn_mfma_f32_16x16x32_bf16(
                bf[ks & 3], aw[(2 * ks - 3) & 7], acc[3], 0, 0, 0);
            acc[2] = __builtin_amdgcn_mfma_f32_16x16x32_bf16(
                bf[ks & 3], aw[(2 * ks - 2) & 7], acc[2], 0, 0, 0);
            if (ks < 15) {
                aw[(2 * ks + 1) & 7] = xo[SIG(E0 + 16 * (2 * ks + 1))];
                aw[(2 * ks + 2) & 7] = xo[SIG(E0 + 16 * (2 * ks + 2))];
            }
            acc[1] = __builtin_amdgcn_mfma_f32_16x16x32_bf16(
                bf[ks & 3], aw[(2 * ks - 1) & 7], acc[1], 0, 0, 0);
            acc[0] = __builtin_amdgcn_mfma_f32_16x16x32_bf16(
                bf[ks & 3], aw[(2 * ks) & 7], acc[0], 0, 0, 0);
        }

        // epilogue: D row = o (g*4 + r contiguous), col = t (lrow)
        float* op = out + (size_t)b * 262144;
        #pragma unroll
        for (int mi = 0; mi < 4; ++mi) {
            const int t = t0w + mi * 16 + lrow;
            *(float4v*)(op + t * 512 + ocol) = acc[mi] + gacc[mi];
        }

        // write next buffer; lgkm-only barrier so global stores keep draining
        if (bi + 1 < NB) {
            short8v* xw = xbuf[p ^ 1];
            xw[tid] = nx0;
            xw[tid + 512] = nx1;
            if (tid < 192) xw[tid + 1024] = nx2;
            asm volatile("s_waitcnt lgkmcnt(0)" ::: "memory");
            __builtin_amdgcn_s_barrier();
            p ^= 1;
        }
    }
}

extern "C" void kernel_launch(void* const* d_in, const int* in_sizes, int n_in,
                              void* d_out, int out_size, void* d_ws, size_t ws_size,
                              hipStream_t stream) {
    const float* x  = (const float*)d_in[0];   // [256,512,1]
    const float* A  = (const float*)d_in[1];   // [512]
    const float* B  = (const float*)d_in[2];   // [1,512]
    const float* C  = (const float*)d_in[3];   // [512,512]
    const float* M  = (const float*)d_in[4];   // [512,1,5]
    const float* h0 = (const float*)d_in[5];   // [512]
    float* out = (float*)d_out;

    char* ws = (char*)d_ws;
    float*          PBT = (float*)ws;                              // 1 MB
    float*          PHT = (float*)(ws + (1u << 20));               // 1 MB
    unsigned short* KT  = (unsigned short*)(ws + (2u << 20));      // 512 KB
    float*          G   = (float*)(ws + (2u << 20) + (1u << 19));  // 1 MB
    short8v*        XS  = (short8v*)(ws + (3u << 20) + (1u << 19));// ~4.75 MB

    k_tables<<<512, 512, 0, stream>>>(A, B, h0, PBT, PHT);
    k_xprep<<<256, 256, 0, stream>>>(x, XS);
    k_ktg<<<dim3(128, 8), 256, 0, stream>>>(C, M, PBT, PHT, KT, G);
    k_main<<<dim3(8, 4, 256 / NB), 512, 0, stream>>>(XS, KT, G, out);
}